// Round 4
// baseline (1951.262 us; speedup 1.0000x reference)
//
#include <hip/hip_runtime.h>

// LSTM B=128,T=1024,H=128,D=64,L=3.
// R4: NB=2, WG=256 (1 wave/SIMD) -> gate-VALU phase per SIMD halved, 4-wave
// barrier, 512B h exchange (batch replicated x8 in A rows, broadcast reads).
// Whh B-frags 128 VGPR/thread, register-prefetched xg, lgkm-only barrier.

#define BATCH 128
#define TT    1024
#define HH    128
#define DD    64
#define NB    2        // batches per recurrence WG
#define PD    4        // xg register prefetch depth (steps)

typedef __attribute__((ext_vector_type(4))) float f32x4;
typedef __attribute__((ext_vector_type(8))) short bf16x8;
typedef __attribute__((ext_vector_type(4))) short bf16x4;

__device__ inline unsigned short f2bf(float f) {           // RNE
  unsigned u = __builtin_bit_cast(unsigned, f);
  u += 0x7FFFu + ((u >> 16) & 1u);
  return (unsigned short)(u >> 16);
}
__device__ inline float bf2f(unsigned short s) {
  return __builtin_bit_cast(float, (unsigned)s << 16);
}
__device__ inline float fsig(float x) {
  return __builtin_amdgcn_rcpf(1.f + __builtin_amdgcn_exp2f(-1.442695041f * x));
}
__device__ inline float ftanh(float x) {
  return 2.f * __builtin_amdgcn_rcpf(1.f + __builtin_amdgcn_exp2f(-2.885390082f * x)) - 1.f;
}
__device__ inline bf16x8 pack8(f32x4 a, f32x4 b) {
  bf16x8 r;
  r[0]=(short)f2bf(a[0]); r[1]=(short)f2bf(a[1]); r[2]=(short)f2bf(a[2]); r[3]=(short)f2bf(a[3]);
  r[4]=(short)f2bf(b[0]); r[5]=(short)f2bf(b[1]); r[6]=(short)f2bf(b[2]); r[7]=(short)f2bf(b[3]);
  return r;
}
// LDS-only barrier: does NOT drain vmcnt -> global prefetch stays in flight.
__device__ inline void bar_lds() {
  asm volatile("s_waitcnt lgkmcnt(0)\n\ts_barrier" ::: "memory");
}

// ---------------- fp32 -> bf16 convert ----------------
__global__ void cvt_bf16(const float* __restrict__ x, unsigned short* __restrict__ xb, int n) {
  int i = (blockIdx.x * 256 + threadIdx.x) * 4;
  if (i < n) {
    f32x4 v = *(const f32x4*)(x + i);
    bf16x4 s;
    s[0]=(short)f2bf(v[0]); s[1]=(short)f2bf(v[1]); s[2]=(short)f2bf(v[2]); s[3]=(short)f2bf(v[3]);
    *(bf16x4*)(xb + i) = s;
  }
}

// ---------------- xg GEMM: [BT x K] @ [K x 512] + bias -> bf16 ----------------
// Output layout: xg[row][j][q] (row=b*T+t, j=hidden unit, q=gate) -> one 8B
// load per thread per recurrence step.
template<int K>
__global__ __launch_bounds__(256, 2) void xg_gemm(
    const unsigned short* __restrict__ A,     // [BT][K] bf16
    const float* __restrict__ Wih,            // [512][K] fp32
    const float* __restrict__ bih, const float* __restrict__ bhh,
    unsigned short* __restrict__ xg)          // [BT][128][4] bf16
{
  constexpr int KC = K / 32;
  constexpr int ASTR = K * 2 + 16;
  __shared__ char alds[64 * ASTR];
  int tid = threadIdx.x, wave = tid >> 6, lane = tid & 63, quad = lane >> 4, l15 = lane & 15;
  size_t M0 = (size_t)blockIdx.x * 64;

#pragma unroll
  for (int v = 0; v < (64 * K) / (256 * 8); ++v) {
    int e = (tid + v * 256) * 8;
    int row = e / K, col = e % K;
    bf16x8 d = *(const bf16x8*)(A + M0 * K + e);
    *(bf16x8*)(alds + row * ASTR + col * 2) = d;
  }
  __syncthreads();

  bf16x8 af[4][KC];
#pragma unroll
  for (int mt = 0; mt < 4; ++mt)
#pragma unroll
    for (int kc = 0; kc < KC; ++kc)
      af[mt][kc] = *(const bf16x8*)(alds + (mt * 16 + l15) * ASTR + quad * 16 + kc * 64);

#pragma unroll
  for (int half = 0; half < 2; ++half) {
    int j = wave * 32 + half * 16 + l15;
    f32x4 acc[4][4];                         // [q][mt]
#pragma unroll
    for (int q = 0; q < 4; ++q) {
      bf16x8 bfr[KC];
#pragma unroll
      for (int kc = 0; kc < KC; ++kc) {
        const float* p = Wih + (size_t)(q * 128 + j) * K + quad * 8 + kc * 32;
        bfr[kc] = pack8(*(const f32x4*)p, *(const f32x4*)(p + 4));
      }
#pragma unroll
      for (int mt = 0; mt < 4; ++mt) acc[q][mt] = (f32x4){0.f,0.f,0.f,0.f};
#pragma unroll
      for (int kc = 0; kc < KC; ++kc)
#pragma unroll
        for (int mt = 0; mt < 4; ++mt)
          acc[q][mt] = __builtin_amdgcn_mfma_f32_16x16x32_bf16(af[mt][kc], bfr[kc], acc[q][mt], 0, 0, 0);
    }
    float bs[4];
#pragma unroll
    for (int q = 0; q < 4; ++q) bs[q] = bih[q * 128 + j] + bhh[q * 128 + j];
#pragma unroll
    for (int mt = 0; mt < 4; ++mt)
#pragma unroll
      for (int r = 0; r < 4; ++r) {
        size_t row = M0 + mt * 16 + quad * 4 + r;
        bf16x4 o;
#pragma unroll
        for (int q = 0; q < 4; ++q) o[q] = (short)f2bf(acc[q][mt][r] + bs[q]);
        *(bf16x4*)(xg + row * 512 + j * 4) = o;
      }
  }
}

// ---------------- recurrence ----------------
// WG=256 (4 waves, 1/SIMD), NB=2. Thread (wave,quad,l15):
//   b = quad>>1, jh = quad&1, j = wave*32 + jh*16 + l15   (one gate chain/lane)
// h exchange: hbuf[b][k] bf16 at byte b*256 + k*2 (512 B/buffer, dbuf).
// A row m = h[m>>3] (batch replicated 8x). A-frag read (m=l15, k=quad*8+kc*32+e):
//   byte (l15>>3)*256 + quad*16 + kc*64 -> 8-lane broadcast, conflict-free.
// Wave covers n-tiles q*128 + wave*32 + h*16 (q=0..3,h=0..1): 32 MFMA/wave.
// C reg0 of quad qd = row qd*4 -> batch qd>>1; lane picks tile h==jh.
template<int IS_LAST>
__global__ __launch_bounds__(256, 1) void lstm_rec(
    const unsigned short* __restrict__ xg,    // [B][T][128][4] bf16
    const float* __restrict__ Whh,            // [512][128]
    const float* __restrict__ h0, const float* __restrict__ c0,
    float* __restrict__ hN, float* __restrict__ cN,
    unsigned short* __restrict__ y_out,       // [B][T][128] bf16 (layers 0,1)
    float* __restrict__ outp,                 // [B][T] (layer 2)
    const float* __restrict__ Wout, const float* __restrict__ boutp)
{
  __shared__ __align__(16) char hA[2][512];
  int tid = threadIdx.x, wave = tid >> 6, lane = tid & 63, quad = lane >> 4, l15 = lane & 15;
  int bg0 = blockIdx.x * NB;
  int b = quad >> 1;
  int jh = quad & 1;
  int j = wave * 32 + jh * 16 + l15;
  int gb = bg0 + b;

  // B-frags: 4 gates x 2 h-tiles x 4 kc = 128 VGPR
  bf16x8 bw[4][2][4];
#pragma unroll
  for (int q = 0; q < 4; ++q)
#pragma unroll
    for (int h = 0; h < 2; ++h)
#pragma unroll
      for (int kc = 0; kc < 4; ++kc) {
        const float* p = Whh + (size_t)(q * 128 + wave * 32 + h * 16 + l15) * HH + quad * 8 + kc * 32;
        bw[q][h][kc] = pack8(*(const f32x4*)p, *(const f32x4*)(p + 4));
      }

  *(unsigned short*)(hA[0] + b * 256 + j * 2) = f2bf(h0[(size_t)gb * HH + j]);
  float cc = c0[(size_t)gb * HH + j];

  // projection (layer 2): wave 2 -> batch 0, wave 3 -> batch 1
  float pw0 = 0.f, pw1 = 0.f, ob = 0.f;
  int pb = 0;
  if (IS_LAST && wave >= 2) {
    pb = wave - 2;
    pw0 = Wout[lane * 2];
    pw1 = Wout[lane * 2 + 1];
    ob = boutp[0];
  }

  // xg register prefetch, depth PD
  const unsigned short* xp = xg + (size_t)gb * (TT * 512) + j * 4;
  bf16x4 xq[PD];
#pragma unroll
  for (int u = 0; u < PD; ++u) xq[u] = *(const bf16x4*)(xp + u * 512);
  xp += PD * 512;

  unsigned short* yo = nullptr;
  if (!IS_LAST) yo = y_out + (size_t)gb * TT * HH + j;

  bar_lds();

  const f32x4 z4 = {0.f, 0.f, 0.f, 0.f};
  float hv = 0.f;
  int rb = (l15 >> 3) * 256 + quad * 16;

  for (int t4 = 0; t4 < TT / PD; ++t4) {
#pragma unroll
    for (int u = 0; u < PD; ++u) {
      int t = t4 * PD + u;
      char* cur = hA[u & 1];          // holds h_{t-1}
      char* nxt = hA[(u & 1) ^ 1];

      // h A-frags: broadcast reads (128B unique each)
      bf16x8 a0 = *(const bf16x8*)(cur + rb);
      bf16x8 a1 = *(const bf16x8*)(cur + rb + 64);
      bf16x8 a2 = *(const bf16x8*)(cur + rb + 128);
      bf16x8 a3 = *(const bf16x8*)(cur + rb + 192);

      // consume prefetched xg, reissue for t+PD
      float xv0 = bf2f((unsigned short)xq[u][0]);
      float xv1 = bf2f((unsigned short)xq[u][1]);
      float xv2 = bf2f((unsigned short)xq[u][2]);
      float xv3 = bf2f((unsigned short)xq[u][3]);
      if (t4 < TT / PD - 1) xq[u] = *(const bf16x4*)xp;
      xp += 512;

      // 8 independent 4-deep MFMA chains (q,h), interleaved
      f32x4 acc[4][2];
#pragma unroll
      for (int q = 0; q < 4; ++q)
#pragma unroll
        for (int h = 0; h < 2; ++h)
          acc[q][h] = __builtin_amdgcn_mfma_f32_16x16x32_bf16(a0, bw[q][h][0], z4, 0, 0, 0);
#pragma unroll
      for (int q = 0; q < 4; ++q)
#pragma unroll
        for (int h = 0; h < 2; ++h)
          acc[q][h] = __builtin_amdgcn_mfma_f32_16x16x32_bf16(a1, bw[q][h][1], acc[q][h], 0, 0, 0);
#pragma unroll
      for (int q = 0; q < 4; ++q)
#pragma unroll
        for (int h = 0; h < 2; ++h)
          acc[q][h] = __builtin_amdgcn_mfma_f32_16x16x32_bf16(a2, bw[q][h][2], acc[q][h], 0, 0, 0);
#pragma unroll
      for (int q = 0; q < 4; ++q)
#pragma unroll
        for (int h = 0; h < 2; ++h)
          acc[q][h] = __builtin_amdgcn_mfma_f32_16x16x32_bf16(a3, bw[q][h][3], acc[q][h], 0, 0, 0);

      // overlapped projection of h_{t-1} (in cur) for layer 2, waves 2/3
      if (IS_LAST && wave >= 2 && t > 0) {
        unsigned hp = *(const unsigned*)(cur + pb * 256 + lane * 4);
        float s = bf2f((unsigned short)(hp & 0xFFFF)) * pw0
                + bf2f((unsigned short)(hp >> 16)) * pw1;
#pragma unroll
        for (int off = 32; off > 0; off >>= 1) s += __shfl_xor(s, off, 64);
        if (lane == 0) outp[(size_t)(bg0 + pb) * TT + (t - 1)] = fmaxf(s + ob, 0.f);
      }

      // gates + state (fp32); lane uses its own h-tile (jh)
      float g0 = jh ? acc[0][1][0] : acc[0][0][0];
      float g1 = jh ? acc[1][1][0] : acc[1][0][0];
      float g2 = jh ? acc[2][1][0] : acc[2][0][0];
      float g3 = jh ? acc[3][1][0] : acc[3][0][0];
      float gi = fsig(g0 + xv0);
      float gf = fsig(g1 + xv1);
      float gg = ftanh(g2 + xv2);
      float go = fsig(g3 + xv3);
      cc = gf * cc + gi * gg;
      hv = go * ftanh(cc);
      unsigned short hb = f2bf(hv);
      *(unsigned short*)(nxt + b * 256 + j * 2) = hb;
      if (!IS_LAST) yo[(size_t)t * HH] = hb;
      bar_lds();
    }
  }

  hN[(size_t)gb * HH + j] = hv;
  cN[(size_t)gb * HH + j] = cc;

  if (IS_LAST && wave >= 2) {   // h_1023 lives in hA[0]
    unsigned hp = *(const unsigned*)(hA[0] + pb * 256 + lane * 4);
    float s = bf2f((unsigned short)(hp & 0xFFFF)) * pw0
            + bf2f((unsigned short)(hp >> 16)) * pw1;
#pragma unroll
    for (int off = 32; off > 0; off >>= 1) s += __shfl_xor(s, off, 64);
    if (lane == 0) outp[(size_t)(bg0 + pb) * TT + (TT - 1)] = fmaxf(s + ob, 0.f);
  }
}

// ---------------- launch ----------------
extern "C" void kernel_launch(void* const* d_in, const int* in_sizes, int n_in,
                              void* d_out, int out_size, void* d_ws, size_t ws_size,
                              hipStream_t stream) {
  const float* x  = (const float*)d_in[0];
  const float* h0 = (const float*)d_in[1];
  const float* c0 = (const float*)d_in[2];
  const float* Wih[3] = {(const float*)d_in[3], (const float*)d_in[7],  (const float*)d_in[11]};
  const float* Whh[3] = {(const float*)d_in[4], (const float*)d_in[8],  (const float*)d_in[12]};
  const float* bih[3] = {(const float*)d_in[5], (const float*)d_in[9],  (const float*)d_in[13]};
  const float* bhh[3] = {(const float*)d_in[6], (const float*)d_in[10], (const float*)d_in[14]};
  const float* Wout = (const float*)d_in[15];
  const float* bout = (const float*)d_in[16];

  float* outp = (float*)d_out;                 // [B][T]
  float* hN = outp + BATCH * TT;               // [L][B][H]
  float* cN = hN + 3 * BATCH * HH;

  char* ws = (char*)d_ws;
  unsigned short* x_bf = (unsigned short*)ws;                      // 16 MB
  unsigned short* y_bf = (unsigned short*)(ws + (size_t)16777216); // 32 MB
  unsigned short* xg   = (unsigned short*)(ws + (size_t)50331648); // 128 MB

  cvt_bf16<<<8192, 256, 0, stream>>>(x, x_bf, BATCH * TT * DD);

  xg_gemm<64><<<2048, 256, 0, stream>>>(x_bf, Wih[0], bih[0], bhh[0], xg);
  lstm_rec<0><<<BATCH / NB, 256, 0, stream>>>(xg, Whh[0], h0, c0,
                                              hN, cN, y_bf, nullptr, Wout, bout);

  xg_gemm<128><<<2048, 256, 0, stream>>>(y_bf, Wih[1], bih[1], bhh[1], xg);
  lstm_rec<0><<<BATCH / NB, 256, 0, stream>>>(xg, Whh[1], h0 + BATCH * HH, c0 + BATCH * HH,
                                              hN + BATCH * HH, cN + BATCH * HH, y_bf, nullptr, Wout, bout);

  xg_gemm<128><<<2048, 256, 0, stream>>>(y_bf, Wih[2], bih[2], bhh[2], xg);
  lstm_rec<1><<<BATCH / NB, 256, 0, stream>>>(xg, Whh[2], h0 + 2 * BATCH * HH, c0 + 2 * BATCH * HH,
                                              hN + 2 * BATCH * HH, cN + 2 * BATCH * HH, nullptr, outp, Wout, bout);
}

// Round 5
// 1778.434 us; speedup vs baseline: 1.0972x; 1.0972x over previous
//
#include <hip/hip_runtime.h>

// LSTM B=128,T=1024,H=128,D=64,L=3 — fully fused, layer-pipelined.
// One kernel, 96 WGs = 3 layers x 32 batch-groups (NB=4, WG=512).
// Layer l+1 group g consumes y_l chunks (8 steps) via agent-scope
// release/acquire flags; per-chunk fused GEMM (Wih in VGPR B-frags) fills an
// LDS xg buffer; recurrence steps = R3 structure (compressed 1KB h exchange,
// lgkm-only barrier, Whh B-frags in VGPRs).

#define BATCH 128
#define TT    1024
#define HH    128
#define DD    64
#define NB    4
#define CH    8                 // chunk steps
#define NG    32                // batch groups per layer
#define BSTR  (CH * 1024 + 8)   // xg LDS: bytes per batch block

typedef __attribute__((ext_vector_type(4))) float f32x4;
typedef __attribute__((ext_vector_type(8))) short bf16x8;
typedef __attribute__((ext_vector_type(4))) short bf16x4;

__device__ inline unsigned short f2bf(float f) {           // RNE
  unsigned u = __builtin_bit_cast(unsigned, f);
  u += 0x7FFFu + ((u >> 16) & 1u);
  return (unsigned short)(u >> 16);
}
__device__ inline float bf2f(unsigned short s) {
  return __builtin_bit_cast(float, (unsigned)s << 16);
}
__device__ inline float fsig(float x) {
  return __builtin_amdgcn_rcpf(1.f + __builtin_amdgcn_exp2f(-1.442695041f * x));
}
__device__ inline float ftanh(float x) {
  return 2.f * __builtin_amdgcn_rcpf(1.f + __builtin_amdgcn_exp2f(-2.885390082f * x)) - 1.f;
}
__device__ inline bf16x8 pack8(f32x4 a, f32x4 b) {
  bf16x8 r;
  r[0]=(short)f2bf(a[0]); r[1]=(short)f2bf(a[1]); r[2]=(short)f2bf(a[2]); r[3]=(short)f2bf(a[3]);
  r[4]=(short)f2bf(b[0]); r[5]=(short)f2bf(b[1]); r[6]=(short)f2bf(b[2]); r[7]=(short)f2bf(b[3]);
  return r;
}
// LDS-only barrier: does NOT drain vmcnt -> global stores stay in flight.
__device__ inline void bar_lds() {
  asm volatile("s_waitcnt lgkmcnt(0)\n\ts_barrier" ::: "memory");
}

__global__ void init_flags(int* f) { if (threadIdx.x < 64) f[threadIdx.x] = 0; }

__global__ __launch_bounds__(512, 2) void lstm_fused(
    const float* __restrict__ x,
    const float* __restrict__ h0, const float* __restrict__ c0,
    const float* __restrict__ Wih0, const float* __restrict__ Whh0,
    const float* __restrict__ bih0, const float* __restrict__ bhh0,
    const float* __restrict__ Wih1, const float* __restrict__ Whh1,
    const float* __restrict__ bih1, const float* __restrict__ bhh1,
    const float* __restrict__ Wih2, const float* __restrict__ Whh2,
    const float* __restrict__ bih2, const float* __restrict__ bhh2,
    const float* __restrict__ Wout, const float* __restrict__ boutp,
    unsigned short* __restrict__ y0, unsigned short* __restrict__ y1,
    float* __restrict__ outp, float* __restrict__ hN, float* __restrict__ cN,
    int* __restrict__ flags)
{
  __shared__ __align__(16) char xqls[NB * BSTR];   // xg chunk: [b][t][j][gate] bf16
  __shared__ __align__(16) char hA[2 * 1024];      // h dbuf, compressed A-order

  const int tid = threadIdx.x, wave = tid >> 6, lane = tid & 63;
  const int quad = lane >> 4, l15 = lane & 15;
  const int layer = blockIdx.x / NG, g = blockIdx.x % NG;
  const int bg0 = g * NB;
  const int gb = bg0 + quad;
  const int j = wave * 16 + l15;

  const float *Wih, *Whh, *bih, *bhh;
  const unsigned short* yin = nullptr;
  unsigned short* yout = nullptr;
  if (layer == 0)      { Wih = Wih0; Whh = Whh0; bih = bih0; bhh = bhh0; yout = y0; }
  else if (layer == 1) { Wih = Wih1; Whh = Whh1; bih = bih1; bhh = bhh1; yin = y0; yout = y1; }
  else                 { Wih = Wih2; Whh = Whh2; bih = bih2; bhh = bhh2; yin = y1; }
  const int Kin = (layer == 0) ? DD : HH;

  // Whh B-frags -> 64 VGPR: tile n = q*128 + j, k = quad*8 + kc*32 + e
  bf16x8 bwh[4][4];
#pragma unroll
  for (int q = 0; q < 4; ++q)
#pragma unroll
    for (int kc = 0; kc < 4; ++kc) {
      const float* p = Whh + (size_t)(q * 128 + j) * HH + quad * 8 + kc * 32;
      bwh[q][kc] = pack8(*(const f32x4*)p, *(const f32x4*)(p + 4));
    }
  // Wih B-frags (K = 64 or 128)
  bf16x8 bwi[4][4];
#pragma unroll
  for (int q = 0; q < 4; ++q)
    for (int kc = 0; kc < Kin / 32; ++kc) {
      const float* p = Wih + (size_t)(q * 128 + j) * Kin + quad * 8 + kc * 32;
      bwi[q][kc] = pack8(*(const f32x4*)p, *(const f32x4*)(p + 4));
    }
  float bs[4];
#pragma unroll
  for (int q = 0; q < 4; ++q) bs[q] = bih[q * 128 + j] + bhh[q * 128 + j];

  // compressed h layout (R3, validated): h[b][k] at byte
  //   (k>>5)*256 + (((k>>3)&3)*4 + b)*16 + (k&7)*2
  int off_w = (wave >> 1) * 256 + (((((wave & 1) << 1) | (l15 >> 3)) * 4) + quad) * 16 + (l15 & 7) * 2;
  int off_r = (quad * 4 + (l15 >> 2)) * 16;

  const float* h0l = h0 + (size_t)layer * BATCH * HH;
  const float* c0l = c0 + (size_t)layer * BATCH * HH;
  *(unsigned short*)(hA + off_w) = f2bf(h0l[(size_t)gb * HH + j]);
  float cc = c0l[(size_t)gb * HH + j];

  // projection setup (layer 2): tid<128, 32 threads per batch
  f32x4 wv = {0.f, 0.f, 0.f, 0.f};
  float ob = 0.f;
  int prd_off = 0, pbl = 0;
  if (layer == 2 && tid < 128) {
    pbl = tid >> 5;
    int j4 = (tid & 31) * 4;
    wv = *(const f32x4*)(Wout + j4);
    ob = boutp[0];
    prd_off = (j4 >> 5) * 256 + ((((j4 >> 3) & 3) * 4) + pbl) * 16 + (j4 & 7) * 2;
  }

  unsigned short* yo = nullptr;
  if (layer < 2) yo = yout + (size_t)gb * TT * HH + j;

  __syncthreads();

  const f32x4 z4 = {0.f, 0.f, 0.f, 0.f};
  float hv = 0.f;

  for (int ck = 0; ck < TT / CH; ++ck) {
    int t0 = ck * CH;

    // ---- consumer: wait for producer chunk ----
    if (layer > 0) {
      if (tid == 0) {
        while (__hip_atomic_load(flags + (layer - 1) * NG + g,
                                 __ATOMIC_ACQUIRE, __HIP_MEMORY_SCOPE_AGENT) <= ck)
          __builtin_amdgcn_s_sleep(1);
      }
      __syncthreads();
    }

    // ---- fused chunk GEMM: xg[b][t][j][q] for t in [t0, t0+CH) ----
    // rows = b*CH + t (32 rows, 2 M-tiles); wave covers n = q*128 + j
#pragma unroll
    for (int mt = 0; mt < 2; ++mt) {
      int row_b = bg0 + mt * 2 + (l15 >> 3);
      int row_t = t0 + (l15 & 7);
      f32x4 acc[4];
      if (layer == 0) {
        const float* ap = x + ((size_t)row_b * TT + row_t) * DD + quad * 8;
        bf16x8 af0 = pack8(*(const f32x4*)ap, *(const f32x4*)(ap + 4));
        bf16x8 af1 = pack8(*(const f32x4*)(ap + 32), *(const f32x4*)(ap + 36));
#pragma unroll
        for (int q = 0; q < 4; ++q) acc[q] = __builtin_amdgcn_mfma_f32_16x16x32_bf16(af0, bwi[q][0], z4, 0, 0, 0);
#pragma unroll
        for (int q = 0; q < 4; ++q) acc[q] = __builtin_amdgcn_mfma_f32_16x16x32_bf16(af1, bwi[q][1], acc[q], 0, 0, 0);
      } else {
        const unsigned short* ap = yin + ((size_t)row_b * TT + row_t) * HH + quad * 8;
        bf16x8 af[4];
#pragma unroll
        for (int kc = 0; kc < 4; ++kc) af[kc] = *(const bf16x8*)(ap + kc * 32);
#pragma unroll
        for (int q = 0; q < 4; ++q) acc[q] = __builtin_amdgcn_mfma_f32_16x16x32_bf16(af[0], bwi[q][0], z4, 0, 0, 0);
#pragma unroll
        for (int kc = 1; kc < 4; ++kc)
#pragma unroll
          for (int q = 0; q < 4; ++q) acc[q] = __builtin_amdgcn_mfma_f32_16x16x32_bf16(af[kc], bwi[q][kc], acc[q], 0, 0, 0);
      }
      // C rows quad*4+r -> b = mt*2 + (quad>>1), t = (quad&1)*4 + r
      int wb = mt * 2 + (quad >> 1);
      char* base = xqls + wb * BSTR + ((quad & 1) * 4) * 1024 + j * 8;
#pragma unroll
      for (int r = 0; r < 4; ++r) {
        bf16x4 o;
#pragma unroll
        for (int q = 0; q < 4; ++q) o[q] = (short)f2bf(acc[q][r] + bs[q]);
        *(bf16x4*)(base + r * 1024) = o;
      }
    }
    bar_lds();

    // ---- CH recurrence steps ----
#pragma unroll
    for (int u = 0; u < CH; ++u) {
      int t = t0 + u;
      char* cur = hA + ((u & 1) << 10);          // t0 even -> u&1 == t&1
      char* nxt = hA + (((u + 1) & 1) << 10);

      // h A-frags: broadcast reads from compressed buffer
      bf16x8 a0 = *(const bf16x8*)(cur + off_r);
      bf16x8 a1 = *(const bf16x8*)(cur + 256 + off_r);
      bf16x8 a2 = *(const bf16x8*)(cur + 512 + off_r);
      bf16x8 a3 = *(const bf16x8*)(cur + 768 + off_r);
      bf16x4 xq4 = *(const bf16x4*)(xqls + quad * BSTR + u * 1024 + j * 8);

      // dual 2-deep MFMA chains per gate
      f32x4 c01[4], c23[4];
#pragma unroll
      for (int q = 0; q < 4; ++q) c01[q] = __builtin_amdgcn_mfma_f32_16x16x32_bf16(a0, bwh[q][0], z4, 0, 0, 0);
#pragma unroll
      for (int q = 0; q < 4; ++q) c23[q] = __builtin_amdgcn_mfma_f32_16x16x32_bf16(a2, bwh[q][2], z4, 0, 0, 0);
#pragma unroll
      for (int q = 0; q < 4; ++q) c01[q] = __builtin_amdgcn_mfma_f32_16x16x32_bf16(a1, bwh[q][1], c01[q], 0, 0, 0);
#pragma unroll
      for (int q = 0; q < 4; ++q) c23[q] = __builtin_amdgcn_mfma_f32_16x16x32_bf16(a3, bwh[q][3], c23[q], 0, 0, 0);

      // overlapped projection of h_{t-1} (in cur), layer 2 only
      if (layer == 2 && t > 0 && tid < 128) {
        bf16x4 hv4 = *(const bf16x4*)(cur + prd_off);
        float s = bf2f((unsigned short)hv4[0]) * wv[0] + bf2f((unsigned short)hv4[1]) * wv[1]
                + bf2f((unsigned short)hv4[2]) * wv[2] + bf2f((unsigned short)hv4[3]) * wv[3];
#pragma unroll
        for (int off = 16; off > 0; off >>= 1) s += __shfl_xor(s, off, 32);
        if ((tid & 31) == 0) outp[(size_t)(bg0 + pbl) * TT + (t - 1)] = fmaxf(s + ob, 0.f);
      }

      // gates + state (fp32); C reg0 = batch quad
      float gi = fsig(c01[0][0] + c23[0][0] + bf2f((unsigned short)xq4[0]));
      float gf = fsig(c01[1][0] + c23[1][0] + bf2f((unsigned short)xq4[1]));
      float gg = ftanh(c01[2][0] + c23[2][0] + bf2f((unsigned short)xq4[2]));
      float go = fsig(c01[3][0] + c23[3][0] + bf2f((unsigned short)xq4[3]));
      cc = gf * cc + gi * gg;
      hv = go * ftanh(cc);
      unsigned short hb = f2bf(hv);
      *(unsigned short*)(nxt + off_w) = hb;
      if (layer < 2) yo[(size_t)t * HH] = hb;
      bar_lds();
    }

    // ---- producer: drain y stores, publish chunk ----
    if (layer < 2) {
      asm volatile("s_waitcnt vmcnt(0)" ::: "memory");
      __syncthreads();
      if (tid == 0)
        __hip_atomic_store(flags + layer * NG + g, ck + 1,
                           __ATOMIC_RELEASE, __HIP_MEMORY_SCOPE_AGENT);
    }
  }

  float* hNl = hN + (size_t)layer * BATCH * HH;
  float* cNl = cN + (size_t)layer * BATCH * HH;
  hNl[(size_t)gb * HH + j] = hv;
  cNl[(size_t)gb * HH + j] = cc;

  if (layer == 2 && tid < 128) {   // h_1023 lives at parity 0
    bf16x4 hv4 = *(const bf16x4*)(hA + prd_off);
    float s = bf2f((unsigned short)hv4[0]) * wv[0] + bf2f((unsigned short)hv4[1]) * wv[1]
            + bf2f((unsigned short)hv4[2]) * wv[2] + bf2f((unsigned short)hv4[3]) * wv[3];
#pragma unroll
    for (int off = 16; off > 0; off >>= 1) s += __shfl_xor(s, off, 32);
    if ((tid & 31) == 0) outp[(size_t)(bg0 + pbl) * TT + (TT - 1)] = fmaxf(s + ob, 0.f);
  }
}

// ---------------- launch ----------------
extern "C" void kernel_launch(void* const* d_in, const int* in_sizes, int n_in,
                              void* d_out, int out_size, void* d_ws, size_t ws_size,
                              hipStream_t stream) {
  const float* x  = (const float*)d_in[0];
  const float* h0 = (const float*)d_in[1];
  const float* c0 = (const float*)d_in[2];
  const float* Wih[3] = {(const float*)d_in[3], (const float*)d_in[7],  (const float*)d_in[11]};
  const float* Whh[3] = {(const float*)d_in[4], (const float*)d_in[8],  (const float*)d_in[12]};
  const float* bih[3] = {(const float*)d_in[5], (const float*)d_in[9],  (const float*)d_in[13]};
  const float* bhh[3] = {(const float*)d_in[6], (const float*)d_in[10], (const float*)d_in[14]};
  const float* Wout = (const float*)d_in[15];
  const float* bout = (const float*)d_in[16];

  float* outp = (float*)d_out;                 // [B][T]
  float* hN = outp + BATCH * TT;               // [L][B][H]
  float* cN = hN + 3 * BATCH * HH;

  char* ws = (char*)d_ws;
  int* flags = (int*)ws;                                            // 64 ints
  unsigned short* y0 = (unsigned short*)(ws + 4096);                // 32 MB
  unsigned short* y1 = (unsigned short*)(ws + 4096 + (size_t)BATCH * TT * HH * 2);

  init_flags<<<1, 64, 0, stream>>>(flags);
  lstm_fused<<<3 * NG, 512, 0, stream>>>(
      x, h0, c0,
      Wih[0], Whh[0], bih[0], bhh[0],
      Wih[1], Whh[1], bih[1], bhh[1],
      Wih[2], Whh[2], bih[2], bhh[2],
      Wout, bout, y0, y1, outp, hN, cN, flags);
}

// Round 6
// 1711.853 us; speedup vs baseline: 1.1399x; 1.0389x over previous
//
#include <hip/hip_runtime.h>

// LSTM B=128,T=1024,H=128,D=64,L=3 — fused, layer-pipelined, R6.
// 96 WGs = 3 layers x 32 groups (NB=4, WG=512). Cross-WG y exchange via
// RELAXED agent-scope atomics (sc0/sc1 -> Infinity Cache, bypassing the
// non-coherent per-XCD L2s) ordered by vmcnt(0)+flag; no release fence on the
// producer (avoids per-chunk buffer_wbl2 = full dirty-L2 writeback, the R5
// 7us/chunk stall). Consumer keeps acquire on the flag only (cheap inv).
// CH=16 steps/chunk. Recurrence core = R3 structure (compressed 1KB h
// exchange, lgkm-only barrier, Whh+Wih B-frags in VGPRs).

#define BATCH 128
#define TT    1024
#define HH    128
#define DD    64
#define NB    4
#define CH    16                // chunk steps
#define NG    32                // batch groups per layer
#define BSTR  (CH * 1024 + 8)   // xg LDS bytes per batch

typedef __attribute__((ext_vector_type(4))) float f32x4;
typedef __attribute__((ext_vector_type(8))) short bf16x8;
typedef __attribute__((ext_vector_type(4))) short bf16x4;

union U8 { unsigned long long q[2]; bf16x8 v; };

__device__ inline unsigned short f2bf(float f) {           // RNE
  unsigned u = __builtin_bit_cast(unsigned, f);
  u += 0x7FFFu + ((u >> 16) & 1u);
  return (unsigned short)(u >> 16);
}
__device__ inline float bf2f(unsigned short s) {
  return __builtin_bit_cast(float, (unsigned)s << 16);
}
__device__ inline float fsig(float x) {
  return __builtin_amdgcn_rcpf(1.f + __builtin_amdgcn_exp2f(-1.442695041f * x));
}
__device__ inline float ftanh(float x) {
  return 2.f * __builtin_amdgcn_rcpf(1.f + __builtin_amdgcn_exp2f(-2.885390082f * x)) - 1.f;
}
__device__ inline bf16x8 pack8(f32x4 a, f32x4 b) {
  bf16x8 r;
  r[0]=(short)f2bf(a[0]); r[1]=(short)f2bf(a[1]); r[2]=(short)f2bf(a[2]); r[3]=(short)f2bf(a[3]);
  r[4]=(short)f2bf(b[0]); r[5]=(short)f2bf(b[1]); r[6]=(short)f2bf(b[2]); r[7]=(short)f2bf(b[3]);
  return r;
}
// LDS-only barrier: does NOT drain vmcnt.
__device__ inline void bar_lds() {
  asm volatile("s_waitcnt lgkmcnt(0)\n\ts_barrier" ::: "memory");
}
__device__ inline unsigned long long yload8(const unsigned short* p) {
  return __hip_atomic_load((unsigned long long*)p, __ATOMIC_RELAXED, __HIP_MEMORY_SCOPE_AGENT);
}

__global__ void init_flags(int* f) { if (threadIdx.x < 64) f[threadIdx.x] = 0; }

__global__ __launch_bounds__(512, 2) void lstm_fused(
    const float* __restrict__ x,
    const float* __restrict__ h0, const float* __restrict__ c0,
    const float* __restrict__ Wih0, const float* __restrict__ Whh0,
    const float* __restrict__ bih0, const float* __restrict__ bhh0,
    const float* __restrict__ Wih1, const float* __restrict__ Whh1,
    const float* __restrict__ bih1, const float* __restrict__ bhh1,
    const float* __restrict__ Wih2, const float* __restrict__ Whh2,
    const float* __restrict__ bih2, const float* __restrict__ bhh2,
    const float* __restrict__ Wout, const float* __restrict__ boutp,
    unsigned short* __restrict__ y0, unsigned short* __restrict__ y1,
    float* __restrict__ outp, float* __restrict__ hN, float* __restrict__ cN,
    int* __restrict__ flags)
{
  __shared__ __align__(16) char xqls[NB * BSTR];   // xg chunk [b][t][j][gate]
  __shared__ __align__(16) char hA[2 * 1024];      // h dbuf, compressed A-order

  const int tid = threadIdx.x, wave = tid >> 6, lane = tid & 63;
  const int quad = lane >> 4, l15 = lane & 15;
  const int layer = blockIdx.x / NG, g = blockIdx.x % NG;
  const int bg0 = g * NB;
  const int gb = bg0 + quad;
  const int j = wave * 16 + l15;

  const float *Wih, *Whh, *bih, *bhh;
  const unsigned short* yin = nullptr;
  unsigned short* yout = nullptr;
  if (layer == 0)      { Wih = Wih0; Whh = Whh0; bih = bih0; bhh = bhh0; yout = y0; }
  else if (layer == 1) { Wih = Wih1; Whh = Whh1; bih = bih1; bhh = bhh1; yin = y0; yout = y1; }
  else                 { Wih = Wih2; Whh = Whh2; bih = bih2; bhh = bhh2; yin = y1; }
  const int Kin = (layer == 0) ? DD : HH;

  // Whh B-frags: tile n = q*128 + j, k = quad*8 + kc*32 + e
  bf16x8 bwh[4][4];
#pragma unroll
  for (int q = 0; q < 4; ++q)
#pragma unroll
    for (int kc = 0; kc < 4; ++kc) {
      const float* p = Whh + (size_t)(q * 128 + j) * HH + quad * 8 + kc * 32;
      bwh[q][kc] = pack8(*(const f32x4*)p, *(const f32x4*)(p + 4));
    }
  // Wih B-frags (K = 64 or 128)
  bf16x8 bwi[4][4];
#pragma unroll
  for (int q = 0; q < 4; ++q)
    for (int kc = 0; kc < Kin / 32; ++kc) {
      const float* p = Wih + (size_t)(q * 128 + j) * Kin + quad * 8 + kc * 32;
      bwi[q][kc] = pack8(*(const f32x4*)p, *(const f32x4*)(p + 4));
    }
  float bs[4];
#pragma unroll
  for (int q = 0; q < 4; ++q) bs[q] = bih[q * 128 + j] + bhh[q * 128 + j];

  // compressed h layout (R3): h[b][k] at byte
  //   (k>>5)*256 + (((k>>3)&3)*4 + b)*16 + (k&7)*2
  int off_w = (wave >> 1) * 256 + (((((wave & 1) << 1) | (l15 >> 3)) * 4) + quad) * 16 + (l15 & 7) * 2;
  int off_r = (quad * 4 + (l15 >> 2)) * 16;

  const float* h0l = h0 + (size_t)layer * BATCH * HH;
  const float* c0l = c0 + (size_t)layer * BATCH * HH;
  *(unsigned short*)(hA + off_w) = f2bf(h0l[(size_t)gb * HH + j]);
  float cc = c0l[(size_t)gb * HH + j];

  // projection setup (layer 2)
  f32x4 wv = {0.f, 0.f, 0.f, 0.f};
  float ob = 0.f;
  int prd_off = 0, pbl = 0;
  if (layer == 2 && tid < 128) {
    pbl = tid >> 5;
    int j4 = (tid & 31) * 4;
    wv = *(const f32x4*)(Wout + j4);
    ob = boutp[0];
    prd_off = (j4 >> 5) * 256 + ((((j4 >> 3) & 3) * 4) + pbl) * 16 + (j4 & 7) * 2;
  }

  unsigned short* yo = nullptr;
  if (layer < 2) yo = yout + (size_t)gb * TT * HH + j;   // j even lanes store pairs

  __syncthreads();

  const f32x4 z4 = {0.f, 0.f, 0.f, 0.f};
  float hv = 0.f;

  for (int ck = 0; ck < TT / CH; ++ck) {
    int t0 = ck * CH;

    // ---- consumer: wait for producer chunk (acquire on flag only) ----
    if (layer > 0) {
      if (tid == 0) {
        while (__hip_atomic_load(flags + (layer - 1) * NG + g,
                                 __ATOMIC_ACQUIRE, __HIP_MEMORY_SCOPE_AGENT) <= ck)
          __builtin_amdgcn_s_sleep(1);
      }
      __syncthreads();
    }

    // ---- fused chunk GEMM: 4 M-tiles, tile mt = batch bg0+mt x 16 steps ----
    if (layer == 0) {
      bf16x8 af[4][2];
#pragma unroll
      for (int mt = 0; mt < 4; ++mt) {
        const float* ap = x + ((size_t)(bg0 + mt) * TT + t0 + l15) * DD + quad * 8;
        af[mt][0] = pack8(*(const f32x4*)ap, *(const f32x4*)(ap + 4));
        af[mt][1] = pack8(*(const f32x4*)(ap + 32), *(const f32x4*)(ap + 36));
      }
#pragma unroll
      for (int mt = 0; mt < 4; ++mt) {
        f32x4 acc[4];
#pragma unroll
        for (int q = 0; q < 4; ++q) acc[q] = __builtin_amdgcn_mfma_f32_16x16x32_bf16(af[mt][0], bwi[q][0], z4, 0, 0, 0);
#pragma unroll
        for (int q = 0; q < 4; ++q) acc[q] = __builtin_amdgcn_mfma_f32_16x16x32_bf16(af[mt][1], bwi[q][1], acc[q], 0, 0, 0);
        char* base = xqls + mt * BSTR + (quad * 4) * 1024 + j * 8;
#pragma unroll
        for (int r = 0; r < 4; ++r) {
          bf16x4 o;
#pragma unroll
          for (int q = 0; q < 4; ++q) o[q] = (short)f2bf(acc[q][r] + bs[q]);
          *(bf16x4*)(base + r * 1024) = o;
        }
      }
    } else {
      // y loads: relaxed agent atomics (IF$-coherent path), all issued first
      U8 af[4][4];
#pragma unroll
      for (int mt = 0; mt < 4; ++mt) {
        const unsigned short* ap = yin + ((size_t)(bg0 + mt) * TT + t0 + l15) * HH + quad * 8;
#pragma unroll
        for (int kc = 0; kc < 4; ++kc) {
          af[mt][kc].q[0] = yload8(ap + kc * 32);
          af[mt][kc].q[1] = yload8(ap + kc * 32 + 4);
        }
      }
#pragma unroll
      for (int mt = 0; mt < 4; ++mt) {
        f32x4 acc[4];
#pragma unroll
        for (int q = 0; q < 4; ++q) acc[q] = __builtin_amdgcn_mfma_f32_16x16x32_bf16(af[mt][0].v, bwi[q][0], z4, 0, 0, 0);
#pragma unroll
        for (int kc = 1; kc < 4; ++kc)
#pragma unroll
          for (int q = 0; q < 4; ++q) acc[q] = __builtin_amdgcn_mfma_f32_16x16x32_bf16(af[mt][kc].v, bwi[q][kc], acc[q], 0, 0, 0);
        char* base = xqls + mt * BSTR + (quad * 4) * 1024 + j * 8;
#pragma unroll
        for (int r = 0; r < 4; ++r) {
          bf16x4 o;
#pragma unroll
          for (int q = 0; q < 4; ++q) o[q] = (short)f2bf(acc[q][r] + bs[q]);
          *(bf16x4*)(base + r * 1024) = o;
        }
      }
    }
    bar_lds();

    // ---- CH recurrence steps ----
#pragma unroll
    for (int u = 0; u < CH; ++u) {
      int t = t0 + u;
      char* cur = hA + ((u & 1) << 10);          // CH even -> u&1 == t&1
      char* nxt = hA + (((u + 1) & 1) << 10);

      bf16x8 a0 = *(const bf16x8*)(cur + off_r);
      bf16x8 a1 = *(const bf16x8*)(cur + 256 + off_r);
      bf16x8 a2 = *(const bf16x8*)(cur + 512 + off_r);
      bf16x8 a3 = *(const bf16x8*)(cur + 768 + off_r);
      bf16x4 xq4 = *(const bf16x4*)(xqls + quad * BSTR + u * 1024 + j * 8);

      f32x4 c01[4], c23[4];
#pragma unroll
      for (int q = 0; q < 4; ++q) c01[q] = __builtin_amdgcn_mfma_f32_16x16x32_bf16(a0, bwh[q][0], z4, 0, 0, 0);
#pragma unroll
      for (int q = 0; q < 4; ++q) c23[q] = __builtin_amdgcn_mfma_f32_16x16x32_bf16(a2, bwh[q][2], z4, 0, 0, 0);
#pragma unroll
      for (int q = 0; q < 4; ++q) c01[q] = __builtin_amdgcn_mfma_f32_16x16x32_bf16(a1, bwh[q][1], c01[q], 0, 0, 0);
#pragma unroll
      for (int q = 0; q < 4; ++q) c23[q] = __builtin_amdgcn_mfma_f32_16x16x32_bf16(a3, bwh[q][3], c23[q], 0, 0, 0);

      if (layer == 2 && t > 0 && tid < 128) {
        bf16x4 hv4 = *(const bf16x4*)(cur + prd_off);
        float s = bf2f((unsigned short)hv4[0]) * wv[0] + bf2f((unsigned short)hv4[1]) * wv[1]
                + bf2f((unsigned short)hv4[2]) * wv[2] + bf2f((unsigned short)hv4[3]) * wv[3];
#pragma unroll
        for (int off = 16; off > 0; off >>= 1) s += __shfl_xor(s, off, 32);
        if ((tid & 31) == 0) outp[(size_t)(bg0 + pbl) * TT + (t - 1)] = fmaxf(s + ob, 0.f);
      }

      float gi = fsig(c01[0][0] + c23[0][0] + bf2f((unsigned short)xq4[0]));
      float gf = fsig(c01[1][0] + c23[1][0] + bf2f((unsigned short)xq4[1]));
      float gg = ftanh(c01[2][0] + c23[2][0] + bf2f((unsigned short)xq4[2]));
      float go = fsig(c01[3][0] + c23[3][0] + bf2f((unsigned short)xq4[3]));
      cc = gf * cc + gi * gg;
      hv = go * ftanh(cc);
      unsigned short hb = f2bf(hv);
      *(unsigned short*)(nxt + off_w) = hb;

      if (layer < 2) {
        // pack (j, j+1) and store as one relaxed agent-scope uint -> IF$
        int hx = __shfl_xor((int)(unsigned)hb, 1);
        if (!(l15 & 1)) {
          unsigned w = ((unsigned)hb & 0xFFFFu) | ((unsigned)hx << 16);
          __hip_atomic_store((unsigned*)(yo + (size_t)t * HH), w,
                             __ATOMIC_RELAXED, __HIP_MEMORY_SCOPE_AGENT);
        }
      }
      bar_lds();
    }

    // ---- producer: drain y stores (vmcnt only), publish chunk ----
    if (layer < 2) {
      asm volatile("s_waitcnt vmcnt(0)" ::: "memory");
      __syncthreads();
      if (tid == 0)
        __hip_atomic_store(flags + layer * NG + g, ck + 1,
                           __ATOMIC_RELAXED, __HIP_MEMORY_SCOPE_AGENT);
    }
  }

  float* hNl = hN + (size_t)layer * BATCH * HH;
  float* cNl = cN + (size_t)layer * BATCH * HH;
  hNl[(size_t)gb * HH + j] = hv;
  cNl[(size_t)gb * HH + j] = cc;

  if (layer == 2 && tid < 128) {   // h_1023 at parity 0
    bf16x4 hv4 = *(const bf16x4*)(hA + prd_off);
    float s = bf2f((unsigned short)hv4[0]) * wv[0] + bf2f((unsigned short)hv4[1]) * wv[1]
            + bf2f((unsigned short)hv4[2]) * wv[2] + bf2f((unsigned short)hv4[3]) * wv[3];
#pragma unroll
    for (int off = 16; off > 0; off >>= 1) s += __shfl_xor(s, off, 32);
    if ((tid & 31) == 0) outp[(size_t)(bg0 + pbl) * TT + (TT - 1)] = fmaxf(s + ob, 0.f);
  }
}

// ---------------- launch ----------------
extern "C" void kernel_launch(void* const* d_in, const int* in_sizes, int n_in,
                              void* d_out, int out_size, void* d_ws, size_t ws_size,
                              hipStream_t stream) {
  const float* x  = (const float*)d_in[0];
  const float* h0 = (const float*)d_in[1];
  const float* c0 = (const float*)d_in[2];
  const float* Wih[3] = {(const float*)d_in[3], (const float*)d_in[7],  (const float*)d_in[11]};
  const float* Whh[3] = {(const float*)d_in[4], (const float*)d_in[8],  (const float*)d_in[12]};
  const float* bih[3] = {(const float*)d_in[5], (const float*)d_in[9],  (const float*)d_in[13]};
  const float* bhh[3] = {(const float*)d_in[6], (const float*)d_in[10], (const float*)d_in[14]};
  const float* Wout = (const float*)d_in[15];
  const float* bout = (const float*)d_in[16];

  float* outp = (float*)d_out;                 // [B][T]
  float* hN = outp + BATCH * TT;               // [L][B][H]
  float* cN = hN + 3 * BATCH * HH;

  char* ws = (char*)d_ws;
  int* flags = (int*)ws;                                            // 64 ints
  unsigned short* y0 = (unsigned short*)(ws + 4096);                // 32 MB
  unsigned short* y1 = (unsigned short*)(ws + 4096 + (size_t)BATCH * TT * HH * 2);

  init_flags<<<1, 64, 0, stream>>>(flags);
  lstm_fused<<<3 * NG, 512, 0, stream>>>(
      x, h0, c0,
      Wih[0], Whh[0], bih[0], bhh[0],
      Wih[1], Whh[1], bih[1], bhh[1],
      Wih[2], Whh[2], bih[2], bhh[2],
      Wout, bout, y0, y1, outp, hN, cN, flags);
}